// Round 8
// baseline (1266.320 us; speedup 1.0000x reference)
//
#include <hip/hip_runtime.h>
#include <hip/hip_bf16.h>

// Workspace layout (4B units):
// [deg:N][rowp:N+4][bcur:1024][bsum:4096][csr:int2 x E][A:N*32][B:N*32][h1:N*32][h2:N*32][gbuf:G*32]
// csr_tmp (int2 x E) ALIASES A/B (CSR build completes before pre1 writes A/B).
// h1/h2/gbuf hold non-negative float bit patterns (global atomicMax on uint).

#define NEG_BIG (-3.0e38f)
#define BSHIFT 7
#define BDSTS (1 << BSHIFT)

__global__ __launch_bounds__(256) void pre1_kernel(
    const float* __restrict__ pos, const float* __restrict__ w1a,
    const float* __restrict__ b1a, float* __restrict__ A, float* __restrict__ B,
    float* __restrict__ h1, int N)
{
    int t = blockIdx.x * 256 + threadIdx.x;
    if (t >= N * 32) return;
    int n = t >> 5, c = t & 31;
    float px = pos[2 * n], py = pos[2 * n + 1];
    float w0 = w1a[c], w1 = w1a[32 + c], w2 = w1a[64 + c], w3 = w1a[96 + c];
    A[t] = fmaf(px, w0 + w2, fmaf(py, w1 + w3, b1a[c]));
    B[t] = -(px * w2 + py * w3);
    h1[t] = 0.0f;
}

__global__ __launch_bounds__(256) void pre2_kernel(
    const float* __restrict__ pos, const float* __restrict__ h1,
    const float* __restrict__ w2a, const float* __restrict__ b2a,
    float* __restrict__ A, float* __restrict__ B, float* __restrict__ h2, int N)
{
    int t = blockIdx.x * 256 + threadIdx.x;
    if (t >= N * 32) return;
    int n = t >> 5, c = t & 31;
    float px = pos[2 * n], py = pos[2 * n + 1];
    float wx = w2a[32 * 32 + c], wy = w2a[33 * 32 + c];
    float s = fmaf(px, wx, fmaf(py, wy, b2a[c]));
    const float* hrow = h1 + (size_t)n * 32;
#pragma unroll
    for (int k = 0; k < 32; ++k) s = fmaf(hrow[k], w2a[k * 32 + c], s);
    A[t] = s;
    B[t] = -(px * wx + py * wy);
    h2[t] = 0.0f;
}

__global__ __launch_bounds__(256) void hist_kernel(
    const int* __restrict__ ei, int* __restrict__ deg, int E)
{
    int base = (blockIdx.x * 256 + threadIdx.x) * 4;
    const int* dsts = ei + E;
    if (base + 3 < E) {
        int4 d = *(const int4*)(dsts + base);
        atomicAdd(deg + d.x, 1); atomicAdd(deg + d.y, 1);
        atomicAdd(deg + d.z, 1); atomicAdd(deg + d.w, 1);
    } else {
        for (int i = base; i < E && i < base + 4; ++i) atomicAdd(deg + dsts[i], 1);
    }
}

__global__ __launch_bounds__(256) void scan1_kernel(
    const int* __restrict__ deg, int* __restrict__ rowp,
    int* __restrict__ bsum, int N)
{
    __shared__ int wsum[4];
    int tid = threadIdx.x, lane = tid & 63, wv = tid >> 6;
    int base = blockIdx.x * 1024 + tid * 4;
    int v0 = 0, v1 = 0, v2 = 0, v3 = 0;
    if (base + 3 < N) {
        int4 v = *(const int4*)(deg + base);
        v0 = v.x; v1 = v.y; v2 = v.z; v3 = v.w;
    } else if (base < N) {
        v0 = deg[base];
        if (base + 1 < N) v1 = deg[base + 1];
        if (base + 2 < N) v2 = deg[base + 2];
    }
    int s = v0 + v1 + v2 + v3;
    int x = s;
#pragma unroll
    for (int d = 1; d < 64; d <<= 1) {
        int t = __shfl_up(x, d, 64);
        if (lane >= d) x += t;
    }
    if (lane == 63) wsum[wv] = x;
    __syncthreads();
    int add = 0;
#pragma unroll
    for (int w = 0; w < 4; ++w) if (w < wv) add += wsum[w];
    int ex = add + x - s;
    if (base < N) {
        rowp[base] = ex;
        if (base + 1 < N) rowp[base + 1] = ex + v0;
        if (base + 2 < N) rowp[base + 2] = ex + v0 + v1;
        if (base + 3 < N) rowp[base + 3] = ex + v0 + v1 + v2;
    }
    if (tid == 255) bsum[blockIdx.x] = add + x;
}

__global__ __launch_bounds__(64) void scan2_kernel(int* __restrict__ bsum, int nb)
{
    int lane = threadIdx.x;
    int total = 0;
    for (int c0 = 0; c0 < nb; c0 += 64) {
        int i = c0 + lane;
        int v = (i < nb) ? bsum[i] : 0;
        int x = v;
#pragma unroll
        for (int d = 1; d < 64; d <<= 1) {
            int t = __shfl_up(x, d, 64);
            if (lane >= d) x += t;
        }
        if (i < nb) bsum[i] = total + x - v;
        total += __shfl(x, 63, 64);
    }
}

__global__ __launch_bounds__(256) void scan3_kernel(
    int* __restrict__ rowp, const int* __restrict__ bsum, int N)
{
    int base = blockIdx.x * 1024 + threadIdx.x * 4;
    int off = bsum[blockIdx.x];
    if (base + 3 < N) {
        int4 v = *(int4*)(rowp + base);
        v.x += off; v.y += off; v.z += off; v.w += off;
        *(int4*)(rowp + base) = v;
    } else if (base < N) {
        rowp[base] += off;
        if (base + 1 < N) rowp[base + 1] += off;
        if (base + 2 < N) rowp[base + 2] += off;
    }
}

// bucket cursors = rowp at bucket boundaries
__global__ __launch_bounds__(256) void bcur_init_kernel(
    const int* __restrict__ rowp, int* __restrict__ bcur, int NB)
{
    int b = blockIdx.x * 256 + threadIdx.x;
    if (b < NB) bcur[b] = rowp[b << BSHIFT];
}

// Pass 1: append edges to their dst-bucket region (consecutive addresses per
// bucket -> full-line writes; ~NB open lines stay L2-resident).
__global__ __launch_bounds__(256) void bucket_scatter_kernel(
    const int* __restrict__ ei, int* __restrict__ bcur,
    int2* __restrict__ csr_tmp, int E)
{
    int base = (blockIdx.x * 256 + threadIdx.x) * 4;
    if (base >= E) return;
    const int* dsts = ei + E;
    if (base + 3 < E) {
        int4 s = *(const int4*)(ei + base);
        int4 d = *(const int4*)(dsts + base);
        int p0 = atomicAdd(bcur + (d.x >> BSHIFT), 1); csr_tmp[p0] = make_int2(s.x, d.x);
        int p1 = atomicAdd(bcur + (d.y >> BSHIFT), 1); csr_tmp[p1] = make_int2(s.y, d.y);
        int p2 = atomicAdd(bcur + (d.z >> BSHIFT), 1); csr_tmp[p2] = make_int2(s.z, d.z);
        int p3 = atomicAdd(bcur + (d.w >> BSHIFT), 1); csr_tmp[p3] = make_int2(s.w, d.w);
    } else {
        for (int i = base; i < E && i < base + 4; ++i) {
            int d = dsts[i];
            int p = atomicAdd(bcur + (d >> BSHIFT), 1);
            csr_tmp[p] = make_int2(ei[i], d);
        }
    }
}

// Pass 2: one block per bucket; per-dst cursors in LDS; writes land in the
// bucket's contiguous output window (L2-resident), reads sequential.
__global__ __launch_bounds__(256) void bucket_sort_kernel(
    const int2* __restrict__ csr_tmp, const int* __restrict__ rowp,
    int2* __restrict__ csr, int N, int E)
{
    __shared__ int lcur[BDSTS];
    int bb = blockIdx.x;
    int d0 = bb << BSHIFT;
    int dend = min(d0 + BDSTS, N);
    int tid = threadIdx.x;
    if (tid < BDSTS) {
        int d = d0 + tid;
        lcur[tid] = (d < N) ? rowp[d] : 0;
    }
    __syncthreads();
    int start = rowp[d0];
    int end = (dend >= N) ? E : rowp[dend];
    for (int i = start + tid; i < end; i += 256) {
        int2 rec = csr_tmp[i];
        int p = atomicAdd(&lcur[rec.y - d0], 1);
        csr[p] = rec;
    }
}

// Edge-centric layer: 256 edges/block, one full output row per thread.
__global__ __launch_bounds__(256, 4) void edge_layer_kernel(
    const int2* __restrict__ csr, const float* __restrict__ A,
    const float* __restrict__ B, const float* __restrict__ w,
    const float* __restrict__ bias, unsigned int* __restrict__ hout, int E)
{
    __shared__ float sM[256 * 36];
    __shared__ int sdst[256];

    int tid = threadIdx.x;
    int e = blockIdx.x * 256 + tid;
    bool valid = e < E;

    int src = 0, dst = -1;
    if (valid) { int2 sd = csr[e]; src = sd.x; dst = sd.y; }
    sdst[tid] = dst;
    int gidx = valid ? dst : 0;

    const float4* Aq = (const float4*)(A + (size_t)src * 32);
    const float4* Bq = (const float4*)(B + (size_t)gidx * 32);
    float4 av[8], bv[8];
#pragma unroll
    for (int q = 0; q < 8; ++q) av[q] = Aq[q];
#pragma unroll
    for (int q = 0; q < 8; ++q) bv[q] = Bq[q];

    float m[32];
#pragma unroll
    for (int j = 0; j < 32; ++j) m[j] = 0.0f;

#pragma unroll
    for (int q = 0; q < 8; ++q) {
        float h0 = fmaxf(av[q].x + bv[q].x, 0.0f);
        float h1 = fmaxf(av[q].y + bv[q].y, 0.0f);
        float h2 = fmaxf(av[q].z + bv[q].z, 0.0f);
        float h3 = fmaxf(av[q].w + bv[q].w, 0.0f);
        const float* wr = w + (4 * q) * 32;        // wave-uniform -> s_load
#pragma unroll
        for (int j = 0; j < 32; ++j) m[j] = fmaf(h0, wr[j], m[j]);
#pragma unroll
        for (int j = 0; j < 32; ++j) m[j] = fmaf(h1, wr[32 + j], m[j]);
#pragma unroll
        for (int j = 0; j < 32; ++j) m[j] = fmaf(h2, wr[64 + j], m[j]);
#pragma unroll
        for (int j = 0; j < 32; ++j) m[j] = fmaf(h3, wr[96 + j], m[j]);
    }

    float* mrow = sM + tid * 36;
#pragma unroll
    for (int q = 0; q < 8; ++q)
        *(float4*)(mrow + 4 * q) = make_float4(m[4 * q], m[4 * q + 1],
                                               m[4 * q + 2], m[4 * q + 3]);
    __syncthreads();

    int c = tid & 31;
    int g = tid >> 5;
    int s0 = g * 32;
    float bc_ = bias[c];
    float run = NEG_BIG;
    int cur = -2;
#pragma unroll 8
    for (int i = 0; i < 32; ++i) {
        int s = s0 + i;
        int d = sdst[s];
        float v = sM[s * 36 + c];
        if (d != cur) {
            if (cur >= 0) {
                float x = run + bc_;
                if (x > 0.0f)
                    atomicMax(hout + (size_t)cur * 32 + c, __float_as_uint(x));
            }
            cur = d;
            run = v;
        } else {
            run = fmaxf(run, v);
        }
    }
    if (cur >= 0) {
        float x = run + bc_;
        if (x > 0.0f) atomicMax(hout + (size_t)cur * 32 + c, __float_as_uint(x));
    }
}

__global__ __launch_bounds__(256) void pool_kernel(
    const float* __restrict__ h2, const int* __restrict__ batch,
    unsigned int* __restrict__ gbuf, int N)
{
    int g = blockIdx.x, p = blockIdx.y;
    __shared__ int sbound[2];
    __shared__ float red[256];
    if (threadIdx.x < 2) {
        int target = g + (int)threadIdx.x;
        int lo = 0, hi = N;
        while (lo < hi) {
            int mid = (lo + hi) >> 1;
            if (batch[mid] < target) lo = mid + 1; else hi = mid;
        }
        sbound[threadIdx.x] = lo;
    }
    __syncthreads();
    int start = sbound[0], end = sbound[1];
    int c = threadIdx.x & 31, r = threadIdx.x >> 5;
    float mx = 0.0f;
    for (int n = start + p * 8 + r; n < end; n += 128)
        mx = fmaxf(mx, h2[(size_t)n * 32 + c]);
    red[threadIdx.x] = mx;
    __syncthreads();
    if (r < 4) red[threadIdx.x] = fmaxf(red[threadIdx.x], red[threadIdx.x + 128]);
    __syncthreads();
    if (r < 2) red[threadIdx.x] = fmaxf(red[threadIdx.x], red[threadIdx.x + 64]);
    __syncthreads();
    if (r == 0) {
        float v = fmaxf(red[threadIdx.x], red[threadIdx.x + 32]);
        if (v > 0.0f) atomicMax(gbuf + g * 32 + c, __float_as_uint(v));
    }
}

__global__ __launch_bounds__(192) void out_kernel(
    const float* __restrict__ gbuf, const float* __restrict__ wc,
    const float* __restrict__ bc, float* __restrict__ out, int G)
{
    int t = threadIdx.x;
    if (t >= G * 3) return;
    int g = t / 3, j = t % 3;
    float s = bc[j];
#pragma unroll
    for (int c = 0; c < 32; ++c)
        s = fmaf(gbuf[g * 32 + c], wc[c * 3 + j], s);
    out[t] = s;
}

extern "C" void kernel_launch(void* const* d_in, const int* in_sizes, int n_in,
                              void* d_out, int out_size, void* d_ws, size_t ws_size,
                              hipStream_t stream) {
    const float* pos = (const float*)d_in[0];
    const float* w1a = (const float*)d_in[1];
    const float* b1a = (const float*)d_in[2];
    const float* w1b = (const float*)d_in[3];
    const float* b1b = (const float*)d_in[4];
    const float* w2a = (const float*)d_in[5];
    const float* b2a = (const float*)d_in[6];
    const float* w2b = (const float*)d_in[7];
    const float* b2b = (const float*)d_in[8];
    const float* wc  = (const float*)d_in[9];
    const float* bc  = (const float*)d_in[10];
    const int* ei    = (const int*)d_in[11];
    const int* batch = (const int*)d_in[12];

    const int N = in_sizes[12];
    const int E = in_sizes[11] / 2;
    const int G = out_size / 3;
    const size_t NC = (size_t)N * 32;
    const int NB = (N + BDSTS - 1) >> BSHIFT;

    int* deg     = (int*)d_ws;
    int* rowp    = deg + N;
    int* bcur    = rowp + (N + 4);
    int* bsum    = bcur + 1024;
    int2* csr    = (int2*)(bsum + 4096);
    float* A     = (float*)(csr + E);
    float* B     = A + NC;
    float* h1    = B + NC;
    float* h2    = h1 + NC;
    float* gbuf  = h2 + NC;
    int2* csr_tmp = (int2*)A;           // aliases A/B: CSR build precedes pre1

    int ncBlocks = ((int)NC + 255) / 256;
    int sBlocks  = (N + 1023) / 1024;
    int e4Blocks = (E + 1023) / 1024;
    int edBlocks = (E + 255) / 256;

    hipMemsetAsync(deg, 0, (size_t)N * sizeof(int), stream);
    hipMemsetAsync(gbuf, 0, (size_t)G * 32 * sizeof(float), stream);

    hist_kernel<<<e4Blocks, 256, 0, stream>>>(ei, deg, E);
    scan1_kernel<<<sBlocks, 256, 0, stream>>>(deg, rowp, bsum, N);
    scan2_kernel<<<1, 64, 0, stream>>>(bsum, sBlocks);
    scan3_kernel<<<sBlocks, 256, 0, stream>>>(rowp, bsum, N);
    bcur_init_kernel<<<(NB + 255) / 256, 256, 0, stream>>>(rowp, bcur, NB);
    bucket_scatter_kernel<<<e4Blocks, 256, 0, stream>>>(ei, bcur, csr_tmp, E);
    bucket_sort_kernel<<<NB, 256, 0, stream>>>(csr_tmp, rowp, csr, N, E);

    pre1_kernel<<<ncBlocks, 256, 0, stream>>>(pos, w1a, b1a, A, B, h1, N);
    edge_layer_kernel<<<edBlocks, 256, 0, stream>>>(csr, A, B, w1b, b1b,
                                                    (unsigned int*)h1, E);
    pre2_kernel<<<ncBlocks, 256, 0, stream>>>(pos, h1, w2a, b2a, A, B, h2, N);
    edge_layer_kernel<<<edBlocks, 256, 0, stream>>>(csr, A, B, w2b, b2b,
                                                    (unsigned int*)h2, E);
    pool_kernel<<<dim3(G, 16), 256, 0, stream>>>(h2, batch,
                                                 (unsigned int*)gbuf, N);
    out_kernel<<<1, 192, 0, stream>>>(gbuf, wc, bc, (float*)d_out, G);
}

// Round 9
// 413.353 us; speedup vs baseline: 3.0635x; 3.0635x over previous
//
#include <hip/hip_runtime.h>
#include <hip/hip_bf16.h>

// Workspace layout (4B units):
// [btot:256][bbase:256][bcur:256][csr_src:E][dst_of:E][A:N*32][B:N*32][h1:N*32][h2:N*32][gbuf:G*32]
// csr_tmp (E ints) ALIASES A (CSR build completes before pre1 writes A).
// h1/h2/gbuf hold non-negative float bit patterns (global atomicMax on uint).
// Records in csr_tmp are packed: src (low 20 bits) | doff (dst within bucket) << 20.

#define NEG_BIG (-3.0e38f)
#define BSHIFT 9
#define BDSTS (1 << BSHIFT)      // 512 dsts per bucket
#define NBMAX 256
#define CHUNK 16384              // edges per block in count/scatter passes

__global__ __launch_bounds__(256) void pre1_kernel(
    const float* __restrict__ pos, const float* __restrict__ w1a,
    const float* __restrict__ b1a, float* __restrict__ A, float* __restrict__ B,
    float* __restrict__ h1, int N)
{
    int t = blockIdx.x * 256 + threadIdx.x;
    if (t >= N * 32) return;
    int n = t >> 5, c = t & 31;
    float px = pos[2 * n], py = pos[2 * n + 1];
    float w0 = w1a[c], w1 = w1a[32 + c], w2 = w1a[64 + c], w3 = w1a[96 + c];
    A[t] = fmaf(px, w0 + w2, fmaf(py, w1 + w3, b1a[c]));
    B[t] = -(px * w2 + py * w3);
    h1[t] = 0.0f;
}

__global__ __launch_bounds__(256) void pre2_kernel(
    const float* __restrict__ pos, const float* __restrict__ h1,
    const float* __restrict__ w2a, const float* __restrict__ b2a,
    float* __restrict__ A, float* __restrict__ B, float* __restrict__ h2, int N)
{
    int t = blockIdx.x * 256 + threadIdx.x;
    if (t >= N * 32) return;
    int n = t >> 5, c = t & 31;
    float px = pos[2 * n], py = pos[2 * n + 1];
    float wx = w2a[32 * 32 + c], wy = w2a[33 * 32 + c];
    float s = fmaf(px, wx, fmaf(py, wy, b2a[c]));
    const float* hrow = h1 + (size_t)n * 32;
#pragma unroll
    for (int k = 0; k < 32; ++k) s = fmaf(hrow[k], w2a[k * 32 + c], s);
    A[t] = s;
    B[t] = -(px * wx + py * wy);
    h2[t] = 0.0f;
}

// Pass 0: per-block LDS bucket histogram -> one global atomicAdd per (block,bucket).
__global__ __launch_bounds__(256) void bucket_count_kernel(
    const int* __restrict__ ei, int* __restrict__ btot, int E, int NB)
{
    __shared__ int bh[NBMAX];
    int tid = threadIdx.x;
    for (int i = tid; i < NB; i += 256) bh[i] = 0;
    __syncthreads();
    const int* dsts = ei + E;
    int base0 = blockIdx.x * CHUNK;
    for (int i = tid * 4; i < CHUNK; i += 1024) {
        int e = base0 + i;
        if (e + 3 < E) {
            int4 d = *(const int4*)(dsts + e);
            atomicAdd(&bh[d.x >> BSHIFT], 1);
            atomicAdd(&bh[d.y >> BSHIFT], 1);
            atomicAdd(&bh[d.z >> BSHIFT], 1);
            atomicAdd(&bh[d.w >> BSHIFT], 1);
        } else {
            for (int k = e; k < E && k < e + 4; ++k)
                atomicAdd(&bh[dsts[k] >> BSHIFT], 1);
        }
    }
    __syncthreads();
    for (int i = tid; i < NB; i += 256)
        if (bh[i]) atomicAdd(btot + i, bh[i]);
}

// Scan bucket totals -> window bases; init cursors. Single block.
__global__ __launch_bounds__(256) void scan_bucket_kernel(
    const int* __restrict__ btot, int* __restrict__ bbase,
    int* __restrict__ bcur, int NB)
{
    __shared__ int ws_[4], wo[4];
    int tid = threadIdx.x, lane = tid & 63, wv = tid >> 6;
    int v = (tid < NB) ? btot[tid] : 0;
    int x = v;
#pragma unroll
    for (int d = 1; d < 64; d <<= 1) {
        int t = __shfl_up(x, d, 64);
        if (lane >= d) x += t;
    }
    if (lane == 63) ws_[wv] = x;
    __syncthreads();
    if (tid == 0) { int r = 0; for (int w = 0; w < 4; ++w) { wo[w] = r; r += ws_[w]; } }
    __syncthreads();
    int ex = wo[wv] + x - v;
    if (tid < NB) { bbase[tid] = ex; bcur[tid] = ex; }
}

// Pass 1: block-local hist -> reserve one chunk per (block,bucket) -> write
// packed records to contiguous chunks (near-full-line writes, low contention).
__global__ __launch_bounds__(256) void bucket_scatter_kernel(
    const int* __restrict__ ei, int* __restrict__ bcur,
    int* __restrict__ csr_tmp, int E, int NB)
{
    __shared__ int lh[NBMAX];
    __shared__ int lb[NBMAX];
    int tid = threadIdx.x;
    for (int i = tid; i < NB; i += 256) lh[i] = 0;
    __syncthreads();
    const int* dsts = ei + E;
    int base0 = blockIdx.x * CHUNK;
    for (int i = tid * 4; i < CHUNK; i += 1024) {
        int e = base0 + i;
        if (e + 3 < E) {
            int4 d = *(const int4*)(dsts + e);
            atomicAdd(&lh[d.x >> BSHIFT], 1);
            atomicAdd(&lh[d.y >> BSHIFT], 1);
            atomicAdd(&lh[d.z >> BSHIFT], 1);
            atomicAdd(&lh[d.w >> BSHIFT], 1);
        } else {
            for (int k = e; k < E && k < e + 4; ++k)
                atomicAdd(&lh[dsts[k] >> BSHIFT], 1);
        }
    }
    __syncthreads();
    for (int i = tid; i < NB; i += 256) {
        int c = lh[i];
        lb[i] = c ? atomicAdd(bcur + i, c) : 0;
    }
    __syncthreads();
    for (int i = tid; i < NB; i += 256) lh[i] = 0;   // reuse as local cursor
    __syncthreads();
    for (int i = tid * 4; i < CHUNK; i += 1024) {
        int e = base0 + i;
        if (e + 3 < E) {
            int4 s = *(const int4*)(ei + e);
            int4 d = *(const int4*)(dsts + e);
            int b, o;
            b = d.x >> BSHIFT; o = atomicAdd(&lh[b], 1);
            csr_tmp[lb[b] + o] = s.x | ((d.x & (BDSTS - 1)) << 20);
            b = d.y >> BSHIFT; o = atomicAdd(&lh[b], 1);
            csr_tmp[lb[b] + o] = s.y | ((d.y & (BDSTS - 1)) << 20);
            b = d.z >> BSHIFT; o = atomicAdd(&lh[b], 1);
            csr_tmp[lb[b] + o] = s.z | ((d.z & (BDSTS - 1)) << 20);
            b = d.w >> BSHIFT; o = atomicAdd(&lh[b], 1);
            csr_tmp[lb[b] + o] = s.w | ((d.w & (BDSTS - 1)) << 20);
        } else {
            for (int k = e; k < E && k < e + 4; ++k) {
                int dd = dsts[k];
                int b = dd >> BSHIFT;
                int o = atomicAdd(&lh[b], 1);
                csr_tmp[lb[b] + o] = ei[k] | ((dd & (BDSTS - 1)) << 20);
            }
        }
    }
}

// Pass 2: one block per bucket. Count per-dst (LDS), 512-wide block scan,
// place csr_src within the bucket's L2-resident window, fill dst_of contiguously.
__global__ __launch_bounds__(256) void bucket_place_kernel(
    const int* __restrict__ csr_tmp, const int* __restrict__ bbase,
    const int* __restrict__ bcur, int* __restrict__ csr_src,
    int* __restrict__ dst_of, int N)
{
    __shared__ int cnt[BDSTS], pre[BDSTS], cur[BDSTS];
    __shared__ int ws_[4], wo[4];
    int b = blockIdx.x, tid = threadIdx.x;
    int d0 = b << BSHIFT;
    int start = bbase[b], end = bcur[b];   // bcur == base+total after pass 1
    for (int i = tid; i < BDSTS; i += 256) cnt[i] = 0;
    __syncthreads();
    for (int i = start + tid; i < end; i += 256)
        atomicAdd(&cnt[csr_tmp[i] >> 20], 1);
    __syncthreads();
    // block exclusive scan of cnt[512]
    int lane = tid & 63, wv = tid >> 6;
    int a0 = cnt[2 * tid], a1 = cnt[2 * tid + 1];
    int s = a0 + a1;
    int x = s;
#pragma unroll
    for (int d = 1; d < 64; d <<= 1) {
        int t = __shfl_up(x, d, 64);
        if (lane >= d) x += t;
    }
    if (lane == 63) ws_[wv] = x;
    __syncthreads();
    if (tid == 0) { int r = 0; for (int w = 0; w < 4; ++w) { wo[w] = r; r += ws_[w]; } }
    __syncthreads();
    int ex = wo[wv] + x - s;
    pre[2 * tid] = ex;       pre[2 * tid + 1] = ex + a0;
    cur[2 * tid] = ex;       cur[2 * tid + 1] = ex + a0;
    __syncthreads();
    for (int i = start + tid; i < end; i += 256) {
        int rec = csr_tmp[i];
        int p = atomicAdd(&cur[rec >> 20], 1);
        csr_src[start + p] = rec & 0xFFFFF;
    }
    for (int t = tid; t < BDSTS; t += 256) {
        int d = d0 + t;
        if (d >= N) break;
        int p = start + pre[t], c = cnt[t];
        for (int k = 0; k < c; ++k) dst_of[p + k] = d;
    }
}

// Edge-centric layer: 256 edges/block, one full output row per thread.
__global__ __launch_bounds__(256, 4) void edge_layer_kernel(
    const int* __restrict__ csr_src, const int* __restrict__ dst_of,
    const float* __restrict__ A, const float* __restrict__ B,
    const float* __restrict__ w, const float* __restrict__ bias,
    unsigned int* __restrict__ hout, int E)
{
    __shared__ float sM[256 * 36];
    __shared__ int sdst[256];

    int tid = threadIdx.x;
    int e = blockIdx.x * 256 + tid;
    bool valid = e < E;

    int src = 0, dst = -1;
    if (valid) { src = csr_src[e]; dst = dst_of[e]; }
    sdst[tid] = dst;
    int gidx = valid ? dst : 0;

    const float4* Aq = (const float4*)(A + (size_t)src * 32);
    const float4* Bq = (const float4*)(B + (size_t)gidx * 32);
    float4 av[8], bv[8];
#pragma unroll
    for (int q = 0; q < 8; ++q) av[q] = Aq[q];
#pragma unroll
    for (int q = 0; q < 8; ++q) bv[q] = Bq[q];

    float m[32];
#pragma unroll
    for (int j = 0; j < 32; ++j) m[j] = 0.0f;

#pragma unroll
    for (int q = 0; q < 8; ++q) {
        float h0 = fmaxf(av[q].x + bv[q].x, 0.0f);
        float h1 = fmaxf(av[q].y + bv[q].y, 0.0f);
        float h2 = fmaxf(av[q].z + bv[q].z, 0.0f);
        float h3 = fmaxf(av[q].w + bv[q].w, 0.0f);
        const float* wr = w + (4 * q) * 32;        // wave-uniform -> s_load
#pragma unroll
        for (int j = 0; j < 32; ++j) m[j] = fmaf(h0, wr[j], m[j]);
#pragma unroll
        for (int j = 0; j < 32; ++j) m[j] = fmaf(h1, wr[32 + j], m[j]);
#pragma unroll
        for (int j = 0; j < 32; ++j) m[j] = fmaf(h2, wr[64 + j], m[j]);
#pragma unroll
        for (int j = 0; j < 32; ++j) m[j] = fmaf(h3, wr[96 + j], m[j]);
    }

    float* mrow = sM + tid * 36;
#pragma unroll
    for (int q = 0; q < 8; ++q)
        *(float4*)(mrow + 4 * q) = make_float4(m[4 * q], m[4 * q + 1],
                                               m[4 * q + 2], m[4 * q + 3]);
    __syncthreads();

    int c = tid & 31;
    int g = tid >> 5;
    int s0 = g * 32;
    float bc_ = bias[c];
    float run = NEG_BIG;
    int cur = -2;
#pragma unroll 8
    for (int i = 0; i < 32; ++i) {
        int s = s0 + i;
        int d = sdst[s];
        float v = sM[s * 36 + c];
        if (d != cur) {
            if (cur >= 0) {
                float x = run + bc_;
                if (x > 0.0f)
                    atomicMax(hout + (size_t)cur * 32 + c, __float_as_uint(x));
            }
            cur = d;
            run = v;
        } else {
            run = fmaxf(run, v);
        }
    }
    if (cur >= 0) {
        float x = run + bc_;
        if (x > 0.0f) atomicMax(hout + (size_t)cur * 32 + c, __float_as_uint(x));
    }
}

__global__ __launch_bounds__(256) void pool_kernel(
    const float* __restrict__ h2, const int* __restrict__ batch,
    unsigned int* __restrict__ gbuf, int N)
{
    int g = blockIdx.x, p = blockIdx.y;
    __shared__ int sbound[2];
    __shared__ float red[256];
    if (threadIdx.x < 2) {
        int target = g + (int)threadIdx.x;
        int lo = 0, hi = N;
        while (lo < hi) {
            int mid = (lo + hi) >> 1;
            if (batch[mid] < target) lo = mid + 1; else hi = mid;
        }
        sbound[threadIdx.x] = lo;
    }
    __syncthreads();
    int start = sbound[0], end = sbound[1];
    int c = threadIdx.x & 31, r = threadIdx.x >> 5;
    float mx = 0.0f;
    for (int n = start + p * 8 + r; n < end; n += 128)
        mx = fmaxf(mx, h2[(size_t)n * 32 + c]);
    red[threadIdx.x] = mx;
    __syncthreads();
    if (r < 4) red[threadIdx.x] = fmaxf(red[threadIdx.x], red[threadIdx.x + 128]);
    __syncthreads();
    if (r < 2) red[threadIdx.x] = fmaxf(red[threadIdx.x], red[threadIdx.x + 64]);
    __syncthreads();
    if (r == 0) {
        float v = fmaxf(red[threadIdx.x], red[threadIdx.x + 32]);
        if (v > 0.0f) atomicMax(gbuf + g * 32 + c, __float_as_uint(v));
    }
}

__global__ __launch_bounds__(192) void out_kernel(
    const float* __restrict__ gbuf, const float* __restrict__ wc,
    const float* __restrict__ bc, float* __restrict__ out, int G)
{
    int t = threadIdx.x;
    if (t >= G * 3) return;
    int g = t / 3, j = t % 3;
    float s = bc[j];
#pragma unroll
    for (int c = 0; c < 32; ++c)
        s = fmaf(gbuf[g * 32 + c], wc[c * 3 + j], s);
    out[t] = s;
}

extern "C" void kernel_launch(void* const* d_in, const int* in_sizes, int n_in,
                              void* d_out, int out_size, void* d_ws, size_t ws_size,
                              hipStream_t stream) {
    const float* pos = (const float*)d_in[0];
    const float* w1a = (const float*)d_in[1];
    const float* b1a = (const float*)d_in[2];
    const float* w1b = (const float*)d_in[3];
    const float* b1b = (const float*)d_in[4];
    const float* w2a = (const float*)d_in[5];
    const float* b2a = (const float*)d_in[6];
    const float* w2b = (const float*)d_in[7];
    const float* b2b = (const float*)d_in[8];
    const float* wc  = (const float*)d_in[9];
    const float* bc  = (const float*)d_in[10];
    const int* ei    = (const int*)d_in[11];
    const int* batch = (const int*)d_in[12];

    const int N = in_sizes[12];
    const int E = in_sizes[11] / 2;
    const int G = out_size / 3;
    const size_t NC = (size_t)N * 32;
    const int NB = (N + BDSTS - 1) >> BSHIFT;

    int* btot    = (int*)d_ws;          // 256
    int* bbase   = btot + 256;          // 256
    int* bcur    = bbase + 256;         // 256
    int* csr_src = bcur + 256;          // E
    int* dst_of  = csr_src + E;         // E
    float* A     = (float*)(dst_of + E);
    float* B     = A + NC;
    float* h1    = B + NC;
    float* h2    = h1 + NC;
    float* gbuf  = h2 + NC;
    int* csr_tmp = (int*)A;             // aliases A: CSR build precedes pre1

    int ncBlocks = ((int)NC + 255) / 256;
    int ebBlocks = (E + CHUNK - 1) / CHUNK;
    int edBlocks = (E + 255) / 256;

    hipMemsetAsync(btot, 0, 256 * sizeof(int), stream);
    hipMemsetAsync(gbuf, 0, (size_t)G * 32 * sizeof(float), stream);

    bucket_count_kernel<<<ebBlocks, 256, 0, stream>>>(ei, btot, E, NB);
    scan_bucket_kernel<<<1, 256, 0, stream>>>(btot, bbase, bcur, NB);
    bucket_scatter_kernel<<<ebBlocks, 256, 0, stream>>>(ei, bcur, csr_tmp, E, NB);
    bucket_place_kernel<<<NB, 256, 0, stream>>>(csr_tmp, bbase, bcur,
                                                csr_src, dst_of, N);

    pre1_kernel<<<ncBlocks, 256, 0, stream>>>(pos, w1a, b1a, A, B, h1, N);
    edge_layer_kernel<<<edBlocks, 256, 0, stream>>>(csr_src, dst_of, A, B,
                                                    w1b, b1b,
                                                    (unsigned int*)h1, E);
    pre2_kernel<<<ncBlocks, 256, 0, stream>>>(pos, h1, w2a, b2a, A, B, h2, N);
    edge_layer_kernel<<<edBlocks, 256, 0, stream>>>(csr_src, dst_of, A, B,
                                                    w2b, b2b,
                                                    (unsigned int*)h2, E);
    pool_kernel<<<dim3(G, 16), 256, 0, stream>>>(h2, batch,
                                                 (unsigned int*)gbuf, N);
    out_kernel<<<1, 192, 0, stream>>>(gbuf, wc, bc, (float*)d_out, G);
}